// Round 1
// baseline (491.079 us; speedup 1.0000x reference)
//
#include <hip/hip_runtime.h>
#include <math.h>

#define N_NODES 100000
#define N_EDGES 1600000
#define DIM 64

// ---------------------------------------------------------------------------
// Kernel 1: per-edge gather + gate + atomic scatter-add.
// One wave (64 lanes) per edge; lane d owns feature d.
//   gate[d] = sigmoid(|curv[r]-curv[c]| * Wc[d] + bc[d])
//   atomicAdd(summed[r*64+d], x[c*64+d] * gate[d]);  lane0: atomicAdd(cnt[r],1)
// ---------------------------------------------------------------------------
__global__ __launch_bounds__(256) void edge_scatter_kernel(
    const float* __restrict__ x,      // [N,64]
    const float* __restrict__ curv,   // [N]
    const float* __restrict__ Wc,     // [64]  (W_curv[:,0])
    const float* __restrict__ bc,     // [64]
    const int*   __restrict__ edge,   // [2*E] row=edge[0:E], col=edge[E:2E]
    float* __restrict__ summed,       // [N,64] accumulator (pre-zeroed)
    float* __restrict__ cnt)          // [N]    accumulator (pre-zeroed)
{
    const int lane = threadIdx.x & 63;
    const int e    = blockIdx.x * 4 + (threadIdx.x >> 6);
    if (e >= N_EDGES) return;

    const int r = edge[e];
    const int c = edge[N_EDGES + e];

    const float cd = fabsf(curv[r] - curv[c]);
    const float z  = cd * Wc[lane] + bc[lane];
    const float gate = 1.0f / (1.0f + expf(-z));

    const float msg = x[(size_t)c * DIM + lane] * gate;
    atomicAdd(&summed[(size_t)r * DIM + lane], msg);
    if (lane == 0) atomicAdd(&cnt[r], 1.0f);
}

// ---------------------------------------------------------------------------
// Kernel 2: mean + Linear(D,D) + exact GELU.
// 4 nodes per 256-thread block. W_lin staged in LDS ([64][65] pad -> only
// 2-way bank aliasing, which is free on CDNA4). Thread (sub,j) computes
// out[node][j] = gelu( sum_d mean[d] * W_lin[j][d] + b_lin[j] ).
// ---------------------------------------------------------------------------
__global__ __launch_bounds__(256) void node_finish_kernel(
    const float* __restrict__ summed, // [N,64]
    const float* __restrict__ cnt,    // [N]
    const float* __restrict__ Wl,     // [64,64] row-major [out_j][in_d]
    const float* __restrict__ bl,     // [64]
    float* __restrict__ out)          // [N,64]
{
    __shared__ float Ws[64][65];
    __shared__ float ms[4][64];

    const int tid = threadIdx.x;

    // Stage W_lin (16 KiB) cooperatively, coalesced.
    #pragma unroll
    for (int i = tid; i < DIM * DIM; i += 256)
        Ws[i >> 6][i & 63] = Wl[i];

    const int sub  = tid >> 6;    // node index within block
    const int j    = tid & 63;    // output feature
    const int node = blockIdx.x * 4 + sub;

    if (node < N_NODES) {
        const float cn  = cnt[node];
        const float inv = 1.0f / fmaxf(cn, 1.0f);
        ms[sub][j] = summed[(size_t)node * DIM + j] * inv;
    }
    __syncthreads();
    if (node >= N_NODES) return;

    float acc = bl[j];
    #pragma unroll
    for (int d = 0; d < DIM; ++d)
        acc = fmaf(ms[sub][d], Ws[j][d], acc);

    // exact GELU: 0.5*x*(1+erf(x/sqrt(2)))
    const float g = 0.5f * acc * (1.0f + erff(acc * 0.70710678118654752f));
    out[(size_t)node * DIM + j] = g;
}

// ---------------------------------------------------------------------------
extern "C" void kernel_launch(void* const* d_in, const int* in_sizes, int n_in,
                              void* d_out, int out_size, void* d_ws, size_t ws_size,
                              hipStream_t stream) {
    const float* x    = (const float*)d_in[0];   // [N,64]
    const float* curv = (const float*)d_in[1];   // [N]
    const float* Wc   = (const float*)d_in[2];   // [64,1]
    const float* bc   = (const float*)d_in[3];   // [64]
    const float* Wl   = (const float*)d_in[4];   // [64,64]
    const float* bl   = (const float*)d_in[5];   // [64]
    const int*   edge = (const int*)d_in[6];     // [2,E] flat

    float* out    = (float*)d_out;
    float* summed = (float*)d_ws;                         // N*64 floats
    float* cnt    = summed + (size_t)N_NODES * DIM;       // N floats

    const size_t acc_bytes = ((size_t)N_NODES * DIM + N_NODES) * sizeof(float);
    hipMemsetAsync(d_ws, 0, acc_bytes, stream);

    // Edge phase: 1 wave/edge, 4 edges per 256-thread block.
    edge_scatter_kernel<<<N_EDGES / 4, 256, 0, stream>>>(
        x, curv, Wc, bc, edge, summed, cnt);

    // Node phase: 4 nodes per 256-thread block.
    node_finish_kernel<<<N_NODES / 4, 256, 0, stream>>>(
        summed, cnt, Wl, bl, out);
}

// Round 2
// 316.428 us; speedup vs baseline: 1.5519x; 1.5519x over previous
//
#include <hip/hip_runtime.h>
#include <math.h>

#define N_NODES 100000
#define N_EDGES 1600000
#define DIM 64

#define SCAN_BS   256                      // threads per scan block
#define SCAN_EPB  1024                     // elements per scan block (4/thread)
#define SCAN_NBLK ((N_NODES + SCAN_EPB - 1) / SCAN_EPB)   // 98

// ---------------------------------------------------------------------------
// 1) Histogram of destination rows. 1.6M int atomics over 400 KB -> cheap.
// ---------------------------------------------------------------------------
__global__ __launch_bounds__(256) void histo_kernel(
    const int* __restrict__ edge, int* __restrict__ cnt)
{
    int e = blockIdx.x * 256 + threadIdx.x;
    if (e < N_EDGES) atomicAdd(&cnt[edge[e]], 1);
}

// ---------------------------------------------------------------------------
// 2a) Per-block reduce of cnt (1024 elems/block).
// ---------------------------------------------------------------------------
__global__ __launch_bounds__(SCAN_BS) void scan_reduce_kernel(
    const int* __restrict__ cnt, int* __restrict__ bsum)
{
    __shared__ int ls[SCAN_BS];
    int base = blockIdx.x * SCAN_EPB;
    int s = 0;
    #pragma unroll
    for (int i = 0; i < 4; ++i) {
        int idx = base + threadIdx.x + i * SCAN_BS;
        s += (idx < N_NODES) ? cnt[idx] : 0;
    }
    ls[threadIdx.x] = s;
    __syncthreads();
    for (int o = SCAN_BS / 2; o > 0; o >>= 1) {
        if (threadIdx.x < o) ls[threadIdx.x] += ls[threadIdx.x + o];
        __syncthreads();
    }
    if (threadIdx.x == 0) bsum[blockIdx.x] = ls[0];
}

// ---------------------------------------------------------------------------
// 2b) Exclusive scan of the 98 block sums (single block).
// ---------------------------------------------------------------------------
__global__ __launch_bounds__(128) void scan_top_kernel(int* __restrict__ bsum)
{
    __shared__ int ls[SCAN_NBLK];
    if (threadIdx.x < SCAN_NBLK) ls[threadIdx.x] = bsum[threadIdx.x];
    __syncthreads();
    if (threadIdx.x == 0) {
        int run = 0;
        for (int i = 0; i < SCAN_NBLK; ++i) { int t = ls[i]; ls[i] = run; run += t; }
    }
    __syncthreads();
    if (threadIdx.x < SCAN_NBLK) bsum[threadIdx.x] = ls[threadIdx.x];
}

// ---------------------------------------------------------------------------
// 2c) Per-block rescan: off[] = exclusive prefix, cursor[] = copy of off[].
// Thread t owns contiguous elements [base + 4t, base + 4t + 4).
// ---------------------------------------------------------------------------
__global__ __launch_bounds__(SCAN_BS) void scan_down_kernel(
    const int* __restrict__ cnt, const int* __restrict__ bsum,
    int* __restrict__ off, int* __restrict__ cursor)
{
    __shared__ int ls[SCAN_BS];
    const int tid  = threadIdx.x;
    const int base = blockIdx.x * SCAN_EPB;

    int v[4]; int tsum = 0;
    #pragma unroll
    for (int i = 0; i < 4; ++i) {
        int idx = base + tid * 4 + i;
        v[i] = (idx < N_NODES) ? cnt[idx] : 0;
        tsum += v[i];
    }
    ls[tid] = tsum;
    __syncthreads();
    // Hillis-Steele inclusive scan over thread sums
    for (int o = 1; o < SCAN_BS; o <<= 1) {
        int t = (tid >= o) ? ls[tid - o] : 0;
        __syncthreads();
        ls[tid] += t;
        __syncthreads();
    }
    int run = bsum[blockIdx.x] + ls[tid] - tsum;   // exclusive thread base
    #pragma unroll
    for (int i = 0; i < 4; ++i) {
        int idx = base + tid * 4 + i;
        if (idx < N_NODES) { off[idx] = run; cursor[idx] = run; }
        run += v[i];
    }
}

// ---------------------------------------------------------------------------
// 3) Scatter edges into CSR order (col + |curv diff| per slot).
// ---------------------------------------------------------------------------
__global__ __launch_bounds__(256) void scatter_kernel(
    const int* __restrict__ edge, const float* __restrict__ curv,
    int* __restrict__ cursor, int* __restrict__ scol, float* __restrict__ scd)
{
    int e = blockIdx.x * 256 + threadIdx.x;
    if (e >= N_EDGES) return;
    int r = edge[e];
    int c = edge[N_EDGES + e];
    float cd = fabsf(curv[r] - curv[c]);
    int pos = atomicAdd(&cursor[r], 1);
    scol[pos] = c;
    scd[pos]  = cd;
}

// ---------------------------------------------------------------------------
// 4) Per-node gather + gate + mean + Linear(D,D) + exact GELU, fused.
// One wave per node (lane = feature d); 4 nodes per 256-thread block.
// ---------------------------------------------------------------------------
__global__ __launch_bounds__(256) void node_kernel(
    const float* __restrict__ x,
    const int*   __restrict__ cnt, const int* __restrict__ off,
    const int*   __restrict__ scol, const float* __restrict__ scd,
    const float* __restrict__ Wc,  const float* __restrict__ bc,
    const float* __restrict__ Wl,  const float* __restrict__ bl,
    float* __restrict__ out)
{
    __shared__ float Ws[64][65];
    __shared__ float ms[4][64];

    const int tid = threadIdx.x;
    #pragma unroll
    for (int i = tid; i < DIM * DIM; i += 256)
        Ws[i >> 6][i & 63] = Wl[i];

    const int sub  = tid >> 6;
    const int d    = tid & 63;
    const int node = blockIdx.x * 4 + sub;

    if (node < N_NODES) {
        const int   deg   = cnt[node];
        const int   start = off[node];
        const float w = Wc[d], b = bc[d];
        float acc = 0.0f;
        int k = 0;
        for (; k + 2 <= deg; k += 2) {               // 2-way unroll for ILP
            int   c0 = scol[start + k],     c1 = scol[start + k + 1];
            float s0 = scd[start + k],      s1 = scd[start + k + 1];
            float g0 = 1.0f / (1.0f + expf(-(s0 * w + b)));
            float g1 = 1.0f / (1.0f + expf(-(s1 * w + b)));
            acc = fmaf(x[(size_t)c0 * DIM + d], g0, acc);
            acc = fmaf(x[(size_t)c1 * DIM + d], g1, acc);
        }
        if (k < deg) {
            int   c0 = scol[start + k];
            float s0 = scd[start + k];
            float g0 = 1.0f / (1.0f + expf(-(s0 * w + b)));
            acc = fmaf(x[(size_t)c0 * DIM + d], g0, acc);
        }
        const float inv = 1.0f / fmaxf((float)deg, 1.0f);
        ms[sub][d] = acc * inv;
    }
    __syncthreads();
    if (node >= N_NODES) return;

    float r = bl[d];
    #pragma unroll
    for (int q = 0; q < DIM; ++q)
        r = fmaf(ms[sub][q], Ws[d][q], r);           // (d+q)%32 -> conflict-free

    out[(size_t)node * DIM + d] = 0.5f * r * (1.0f + erff(r * 0.70710678118654752f));
}

// ---------------------------------------------------------------------------
extern "C" void kernel_launch(void* const* d_in, const int* in_sizes, int n_in,
                              void* d_out, int out_size, void* d_ws, size_t ws_size,
                              hipStream_t stream) {
    const float* x    = (const float*)d_in[0];
    const float* curv = (const float*)d_in[1];
    const float* Wc   = (const float*)d_in[2];
    const float* bc   = (const float*)d_in[3];
    const float* Wl   = (const float*)d_in[4];
    const float* bl   = (const float*)d_in[5];
    const int*   edge = (const int*)d_in[6];

    float* out = (float*)d_out;

    // Workspace layout (~14 MB)
    int*   cnt    = (int*)d_ws;                 // N
    int*   off    = cnt + N_NODES;              // N
    int*   cursor = off + N_NODES;              // N
    int*   bsum   = cursor + N_NODES;           // 128
    int*   scol   = bsum + 128;                 // E
    float* scd    = (float*)(scol + N_EDGES);   // E

    hipMemsetAsync(cnt, 0, N_NODES * sizeof(int), stream);

    const int eblk = (N_EDGES + 255) / 256;     // 6250
    histo_kernel<<<eblk, 256, 0, stream>>>(edge, cnt);
    scan_reduce_kernel<<<SCAN_NBLK, SCAN_BS, 0, stream>>>(cnt, bsum);
    scan_top_kernel<<<1, 128, 0, stream>>>(bsum);
    scan_down_kernel<<<SCAN_NBLK, SCAN_BS, 0, stream>>>(cnt, bsum, off, cursor);
    scatter_kernel<<<eblk, 256, 0, stream>>>(edge, curv, cursor, scol, scd);
    node_kernel<<<N_NODES / 4, 256, 0, stream>>>(
        x, cnt, off, scol, scd, Wc, bc, Wl, bl, out);
}

// Round 3
// 289.755 us; speedup vs baseline: 1.6948x; 1.0921x over previous
//
#include <hip/hip_runtime.h>
#include <math.h>

#define N_NODES 100000
#define N_EDGES 1600000
#define DIM 64

#define SCAN_BS   256
#define SCAN_EPB  1024
#define SCAN_NBLK ((N_NODES + SCAN_EPB - 1) / SCAN_EPB)   // 98

// fast sigmoid via hardware v_exp_f32 / v_rcp_f32.
// gate = 1/(1+exp(-(s*w+b))) = rcp(1 + exp2(s*(-w*log2e) + (-b*log2e)))
__device__ __forceinline__ float fast_gate(float s, float wl, float bl2) {
    return __builtin_amdgcn_rcpf(1.0f + __builtin_amdgcn_exp2f(fmaf(s, wl, bl2)));
}

// ---------------------------------------------------------------------------
// 1) Histogram of destination rows.
// ---------------------------------------------------------------------------
__global__ __launch_bounds__(256) void histo_kernel(
    const int* __restrict__ edge, int* __restrict__ cnt)
{
    int e = blockIdx.x * 256 + threadIdx.x;
    if (e < N_EDGES) atomicAdd(&cnt[edge[e]], 1);
}

// ---------------------------------------------------------------------------
// 2a) Per-block reduce of cnt.
// ---------------------------------------------------------------------------
__global__ __launch_bounds__(SCAN_BS) void scan_reduce_kernel(
    const int* __restrict__ cnt, int* __restrict__ bsum)
{
    __shared__ int ls[SCAN_BS];
    int base = blockIdx.x * SCAN_EPB;
    int s = 0;
    #pragma unroll
    for (int i = 0; i < 4; ++i) {
        int idx = base + threadIdx.x + i * SCAN_BS;
        s += (idx < N_NODES) ? cnt[idx] : 0;
    }
    ls[threadIdx.x] = s;
    __syncthreads();
    for (int o = SCAN_BS / 2; o > 0; o >>= 1) {
        if (threadIdx.x < o) ls[threadIdx.x] += ls[threadIdx.x + o];
        __syncthreads();
    }
    if (threadIdx.x == 0) bsum[blockIdx.x] = ls[0];
}

// ---------------------------------------------------------------------------
// 2b) Exclusive scan of the 98 block sums.
// ---------------------------------------------------------------------------
__global__ __launch_bounds__(128) void scan_top_kernel(int* __restrict__ bsum)
{
    __shared__ int ls[SCAN_NBLK];
    if (threadIdx.x < SCAN_NBLK) ls[threadIdx.x] = bsum[threadIdx.x];
    __syncthreads();
    if (threadIdx.x == 0) {
        int run = 0;
        for (int i = 0; i < SCAN_NBLK; ++i) { int t = ls[i]; ls[i] = run; run += t; }
    }
    __syncthreads();
    if (threadIdx.x < SCAN_NBLK) bsum[threadIdx.x] = ls[threadIdx.x];
}

// ---------------------------------------------------------------------------
// 2c) Per-block rescan -> off[], cursor[].
// ---------------------------------------------------------------------------
__global__ __launch_bounds__(SCAN_BS) void scan_down_kernel(
    const int* __restrict__ cnt, const int* __restrict__ bsum,
    int* __restrict__ off, int* __restrict__ cursor)
{
    __shared__ int ls[SCAN_BS];
    const int tid  = threadIdx.x;
    const int base = blockIdx.x * SCAN_EPB;

    int v[4]; int tsum = 0;
    #pragma unroll
    for (int i = 0; i < 4; ++i) {
        int idx = base + tid * 4 + i;
        v[i] = (idx < N_NODES) ? cnt[idx] : 0;
        tsum += v[i];
    }
    ls[tid] = tsum;
    __syncthreads();
    for (int o = 1; o < SCAN_BS; o <<= 1) {
        int t = (tid >= o) ? ls[tid - o] : 0;
        __syncthreads();
        ls[tid] += t;
        __syncthreads();
    }
    int run = bsum[blockIdx.x] + ls[tid] - tsum;
    #pragma unroll
    for (int i = 0; i < 4; ++i) {
        int idx = base + tid * 4 + i;
        if (idx < N_NODES) { off[idx] = run; cursor[idx] = run; }
        run += v[i];
    }
}

// ---------------------------------------------------------------------------
// 3) Scatter edges into CSR order: one int2 {col, cd_bits} per slot.
// ---------------------------------------------------------------------------
__global__ __launch_bounds__(256) void scatter_kernel(
    const int* __restrict__ edge, const float* __restrict__ curv,
    int* __restrict__ cursor, int2* __restrict__ spair)
{
    int e = blockIdx.x * 256 + threadIdx.x;
    if (e >= N_EDGES) return;
    int r = edge[e];
    int c = edge[N_EDGES + e];
    float cd = fabsf(curv[r] - curv[c]);
    int pos = atomicAdd(&cursor[r], 1);
    spair[pos] = make_int2(c, __float_as_int(cd));
}

// ---------------------------------------------------------------------------
// 4) Per-node gather + fast gate + mean + Linear + exact GELU, fused.
// One wave per node (lane = feature d); 4 nodes per 256-thread block.
// ---------------------------------------------------------------------------
__global__ __launch_bounds__(256) void node_kernel(
    const float* __restrict__ x,
    const int*   __restrict__ cnt, const int* __restrict__ off,
    const int2*  __restrict__ spair,
    const float* __restrict__ Wc,  const float* __restrict__ bc,
    const float* __restrict__ Wl,  const float* __restrict__ bl,
    float* __restrict__ out)
{
    __shared__ float Ws[64][65];
    __shared__ float ms[4][64];

    const int tid = threadIdx.x;
    #pragma unroll
    for (int i = tid; i < DIM * DIM; i += 256)
        Ws[i >> 6][i & 63] = Wl[i];

    const int sub  = tid >> 6;
    const int d    = tid & 63;
    const int node = blockIdx.x * 4 + sub;

    if (node < N_NODES) {
        const int deg   = cnt[node];
        const int start = off[node];
        // hoisted per-lane gate constants: exp(-(s*w+b)) = exp2(s*wl + bl2)
        const float wl  = Wc[d] * -1.44269504088896340736f;
        const float bl2 = bc[d] * -1.44269504088896340736f;

        const int2* sp = spair + start;
        float acc = 0.0f;
        int k = 0;
        for (; k + 4 <= deg; k += 4) {
            int2 p0 = sp[k], p1 = sp[k + 1], p2 = sp[k + 2], p3 = sp[k + 3];
            float g0 = fast_gate(__int_as_float(p0.y), wl, bl2);
            float g1 = fast_gate(__int_as_float(p1.y), wl, bl2);
            float g2 = fast_gate(__int_as_float(p2.y), wl, bl2);
            float g3 = fast_gate(__int_as_float(p3.y), wl, bl2);
            acc = fmaf(x[(unsigned)(p0.x << 6) + d], g0, acc);
            acc = fmaf(x[(unsigned)(p1.x << 6) + d], g1, acc);
            acc = fmaf(x[(unsigned)(p2.x << 6) + d], g2, acc);
            acc = fmaf(x[(unsigned)(p3.x << 6) + d], g3, acc);
        }
        for (; k < deg; ++k) {
            int2 p0 = sp[k];
            float g0 = fast_gate(__int_as_float(p0.y), wl, bl2);
            acc = fmaf(x[(unsigned)(p0.x << 6) + d], g0, acc);
        }
        const float inv = 1.0f / fmaxf((float)deg, 1.0f);
        ms[sub][d] = acc * inv;
    }
    __syncthreads();
    if (node >= N_NODES) return;

    float r = bl[d];
    #pragma unroll
    for (int q = 0; q < DIM; ++q)
        r = fmaf(ms[sub][q], Ws[d][q], r);

    out[(size_t)node * DIM + d] = 0.5f * r * (1.0f + erff(r * 0.70710678118654752f));
}

// ---------------------------------------------------------------------------
extern "C" void kernel_launch(void* const* d_in, const int* in_sizes, int n_in,
                              void* d_out, int out_size, void* d_ws, size_t ws_size,
                              hipStream_t stream) {
    const float* x    = (const float*)d_in[0];
    const float* curv = (const float*)d_in[1];
    const float* Wc   = (const float*)d_in[2];
    const float* bc   = (const float*)d_in[3];
    const float* Wl   = (const float*)d_in[4];
    const float* bl   = (const float*)d_in[5];
    const int*   edge = (const int*)d_in[6];

    float* out = (float*)d_out;

    int*  cnt    = (int*)d_ws;                  // N
    int*  off    = cnt + N_NODES;               // N
    int*  cursor = off + N_NODES;               // N
    int*  bsum   = cursor + N_NODES;            // 128
    int2* spair  = (int2*)(bsum + 128);         // E pairs (12.8 MB)

    hipMemsetAsync(cnt, 0, N_NODES * sizeof(int), stream);

    const int eblk = (N_EDGES + 255) / 256;
    histo_kernel<<<eblk, 256, 0, stream>>>(edge, cnt);
    scan_reduce_kernel<<<SCAN_NBLK, SCAN_BS, 0, stream>>>(cnt, bsum);
    scan_top_kernel<<<1, 128, 0, stream>>>(bsum);
    scan_down_kernel<<<SCAN_NBLK, SCAN_BS, 0, stream>>>(cnt, bsum, off, cursor);
    scatter_kernel<<<eblk, 256, 0, stream>>>(edge, curv, cursor, spair);
    node_kernel<<<N_NODES / 4, 256, 0, stream>>>(
        x, cnt, off, spair, Wc, bc, Wl, bl, out);
}